// Round 12
// baseline (43.317 us; speedup 1.0000x reference)
//
#include <hip/hip_runtime.h>
#include <math.h>

#define B_ 2
#define N_ 20000
#define M_ 1024
#define C_ 256
#define BN_EPS_ 1e-5f

#define NNBLK_PER_B_ 157            // ceil(20000/128), 128 points per NN block
#define GEMM_BLOCKS_ 256            // 16 mt x 4 ot x 4 bh
#define NN_BLOCKS_   (2 * NNBLK_PER_B_)

// index-carrying sorted top-3 insert, strict < keeps earliest (lowest index).
// Cold merge path only.
#define INSERT3(vv0, vv1, vv2, ii0, ii1, ii2, dd, ss)     \
    {                                                     \
        bool c2_ = (dd) < vv2;                            \
        vv2 = c2_ ? (dd) : vv2;  ii2 = c2_ ? (ss) : ii2;  \
        bool c1_ = vv2 < vv1;                             \
        float tv_ = vv1; int ti_ = ii1;                   \
        vv1 = c1_ ? vv2 : vv1;  ii1 = c1_ ? ii2 : ii1;    \
        vv2 = c1_ ? tv_ : vv2; ii2 = c1_ ? ti_ : ii2;     \
        bool c0_ = vv1 < vv0;                             \
        tv_ = vv0; ti_ = ii0;                             \
        vv0 = c0_ ? vv1 : vv0;  ii0 = c0_ ? ii1 : ii0;    \
        vv1 = c0_ ? tv_ : vv1; ii1 = c0_ ? ti_ : ii1;     \
    }

// slim exact hot-loop insert (R9-proven state-identical to INSERT3)
#define SLIM3(vv0, vv1, vv2, ii0, ii1, ii2, dd, gg)       \
    {                                                     \
        const bool c0_ = (dd) < vv0;                      \
        const bool c1_ = (dd) < vv1;                      \
        const bool c2_ = (dd) < vv2;                      \
        ii2 = c2_ ? (c1_ ? ii1 : (gg)) : ii2;             \
        ii1 = c1_ ? (c0_ ? ii0 : (gg)) : ii1;             \
        ii0 = c0_ ? (gg) : ii0;                           \
        const float nv1_ = __builtin_amdgcn_fmed3f((dd), vv0, vv1); \
        const float nv2_ = __builtin_amdgcn_fmed3f((dd), vv1, vv2); \
        vv0 = fminf((dd), vv0);                           \
        vv1 = nv1_;                                       \
        vv2 = nv2_;                                       \
    }

// ---------------------------------------------------------------------------
// Fused kernel: blocks [0,256) run the head GEMMs -> part[],
//               blocks [256,570) run 3-NN (128 points each, 2 per lane)
//               -> nnres[] (packed idx + weights).
// ---------------------------------------------------------------------------
__global__ __launch_bounds__(256) void k_fused(
    const float* __restrict__ pc, const float* __restrict__ seed,
    const float* __restrict__ feat,
    const float* __restrict__ w1f, const float* __restrict__ b1f,
    const float* __restrict__ g1f, const float* __restrict__ be1f,
    const float* __restrict__ mu1f, const float* __restrict__ var1f,
    const float* __restrict__ w2f, const float* __restrict__ b2f,
    const float* __restrict__ w1c, const float* __restrict__ b1c,
    const float* __restrict__ g1c, const float* __restrict__ be1c,
    const float* __restrict__ mu1c, const float* __restrict__ var1c,
    const float* __restrict__ w2c, const float* __restrict__ b2c,
    float* __restrict__ part, uint4* __restrict__ nnres)
{
    __shared__ float4 smembuf[1792];          // 28672 B, union of both roles
    const int bid = blockIdx.x;
    const int tid = threadIdx.x;

    if (bid < GEMM_BLOCKS_) {
        // =================== GEMM role (R11 verbatim) ===================
        const int mt = bid & 15;
        const int ot = (bid >> 4) & 3;
        const int bh = bid >> 6;
        const int b = bh >> 1, head = bh & 1;

        const float* __restrict__ w1   = head ? w1c   : w1f;
        const float* __restrict__ b1   = head ? b1c   : b1f;
        const float* __restrict__ g1   = head ? g1c   : g1f;
        const float* __restrict__ be1  = head ? be1c  : be1f;
        const float* __restrict__ mu1  = head ? mu1c  : mu1f;
        const float* __restrict__ var1 = head ? var1c : var1f;
        const float* __restrict__ w2   = head ? w2c   : w2f;
        const float* __restrict__ b2   = head ? b2c   : b2f;
        const int nj = head ? 3 : 2;

        float* base = (float*)smembuf;
        float (*sW)[68]      = (float(*)[68])base;             // 16x68
        float (*sF)[64]      = (float(*)[64])(base + 1088);    // 16x64
        float (*sred)[3][68] = (float(*)[3][68])(base + 2112); // 16x3x68

        const int tm = tid & 15;
        const int to = tid >> 4;
        const int m0 = mt * 64, o0 = ot * 64;

        const int so  = tid >> 2;
        const int sc4 = (tid & 3) << 2;
        const float sscale = g1[o0 + so] * rsqrtf(var1[o0 + so] + BN_EPS_);
        const int fc = tid >> 4;
        const int fm = (tid & 15) << 2;

        const float* __restrict__ wrow = w1 + (size_t)(o0 + so) * C_ + sc4;
        const float* __restrict__ frow = feat + ((size_t)b * C_ + fc) * M_ + m0 + fm;

        float4 wv = *(const float4*)(wrow);
        float4 fv = *(const float4*)(frow);

        float2 acc2[4][2] = {};

        for (int c0 = 0; c0 < C_; c0 += 16) {
            __syncthreads();
            sW[sc4 + 0][so] = wv.x * sscale;
            sW[sc4 + 1][so] = wv.y * sscale;
            sW[sc4 + 2][so] = wv.z * sscale;
            sW[sc4 + 3][so] = wv.w * sscale;
            *(float4*)&sF[fc][fm] = fv;
            __syncthreads();
            const int cn = (c0 + 16 < C_) ? c0 + 16 : c0;
            wv = *(const float4*)(wrow + cn);
            fv = *(const float4*)(frow + (size_t)cn * M_);
            #pragma unroll
            for (int cc = 0; cc < 16; ++cc) {
                float4 w4 = *(const float4*)&sW[cc][to << 2];
                float4 f4 = *(const float4*)&sF[cc][tm << 2];
                const float2 f01 = make_float2(f4.x, f4.y);
                const float2 f23 = make_float2(f4.z, f4.w);
                float wr[4] = {w4.x, w4.y, w4.z, w4.w};
                #pragma unroll
                for (int i = 0; i < 4; ++i) {
                    const float2 wb = make_float2(wr[i], wr[i]);
                    acc2[i][0] = acc2[i][0] + wb * f01;
                    acc2[i][1] = acc2[i][1] + wb * f23;
                }
            }
        }

        float r[4][4];
        #pragma unroll
        for (int i = 0; i < 4; ++i) {
            const int o = o0 + (to << 2) + i;
            const float sc = g1[o] * rsqrtf(var1[o] + BN_EPS_);
            const float bb = (b1[o] - mu1[o]) * sc + be1[o];
            r[i][0] = fmaxf(acc2[i][0].x + bb, 0.f);
            r[i][1] = fmaxf(acc2[i][0].y + bb, 0.f);
            r[i][2] = fmaxf(acc2[i][1].x + bb, 0.f);
            r[i][3] = fmaxf(acc2[i][1].y + bb, 0.f);
        }

        __syncthreads();
        for (int j = 0; j < nj; ++j) {
            float s[4] = {0.f, 0.f, 0.f, 0.f};
            #pragma unroll
            for (int i = 0; i < 4; ++i) {
                const float w = w2[(size_t)j * C_ + o0 + (to << 2) + i];
                #pragma unroll
                for (int jj = 0; jj < 4; ++jj)
                    s[jj] = fmaf(w, r[i][jj], s[jj]);
            }
            *(float4*)&sred[to][j][tm << 2] = *(float4*)s;
        }
        __syncthreads();

        if (tid < nj * 64) {
            const int j = tid >> 6, m = tid & 63;
            float a = 0.f;
            #pragma unroll
            for (int t = 0; t < 16; ++t) a += sred[t][j][m];
            if (ot == 0) a += b2[j];
            const int jg = head ? (2 + j) : j;
            part[(((size_t)ot * B_ + b) * 5 + jg) * M_ + m0 + m] = a;
        }
    } else {
        // =================== NN role: 128 points, 2 per lane ===================
        const int nb = bid - GEMM_BLOCKS_;
        const int b = (nb >= NNBLK_PER_B_) ? 1 : 0;
        const int p0 = (nb - b * NNBLK_PER_B_) << 7;
        const int wv = tid >> 6, lane = tid & 63;

        float4* sseed = smembuf;                                   // 16384 B
        float* fb = (float*)smembuf;
        float (*smdA)[64][3] = (float(*)[64][3])(fb + 4096);       // 4x64x3
        int   (*smiA)[64][3] = (int(*)[64][3])(fb + 4864);
        float (*smdB)[64][3] = (float(*)[64][3])(fb + 5632);
        int   (*smiB)[64][3] = (int(*)[64][3])(fb + 6400);         // ends 7168

        // stage 4 seeds/thread via 3 coalesced float4 loads (R11-proven)
        {
            const int s4 = tid;
            const float4* __restrict__ sp4 =
                (const float4*)(seed + ((size_t)b * M_ + (size_t)s4 * 4) * 3);
            const float4 a = sp4[0], bq = sp4[1], cq = sp4[2];
            sseed[s4 * 4 + 0] = make_float4(a.x, a.y, a.z,
                0.5f * ((a.x * a.x + a.y * a.y) + a.z * a.z));
            sseed[s4 * 4 + 1] = make_float4(a.w, bq.x, bq.y,
                0.5f * ((a.w * a.w + bq.x * bq.x) + bq.y * bq.y));
            sseed[s4 * 4 + 2] = make_float4(bq.z, bq.w, cq.x,
                0.5f * ((bq.z * bq.z + bq.w * bq.w) + cq.x * cq.x));
            sseed[s4 * 4 + 3] = make_float4(cq.y, cq.z, cq.w,
                0.5f * ((cq.y * cq.y + cq.z * cq.z) + cq.w * cq.w));
        }
        __syncthreads();

        const int pA = p0 + lane;
        const int pB = p0 + 64 + lane;
        const int pclA = (pA < N_) ? pA : (N_ - 1);
        const int pclB = (pB < N_) ? pB : (N_ - 1);
        const float uxA = pc[((size_t)b * N_ + pclA) * 3 + 0];
        const float uyA = pc[((size_t)b * N_ + pclA) * 3 + 1];
        const float uzA = pc[((size_t)b * N_ + pclA) * 3 + 2];
        const float unA = (uxA * uxA + uyA * uyA) + uzA * uzA;
        const float uxB = pc[((size_t)b * N_ + pclB) * 3 + 0];
        const float uyB = pc[((size_t)b * N_ + pclB) * 3 + 1];
        const float uzB = pc[((size_t)b * N_ + pclB) * 3 + 2];
        const float unB = (uxB * uxB + uyB * uyB) + uzB * uzB;

        float a0 = 3.4e38f, a1 = 3.4e38f, a2 = 3.4e38f;
        float b0 = 3.4e38f, b1v = 3.4e38f, b2v = 3.4e38f;
        int ai0 = 0, ai1 = 0, ai2 = 0;
        int bi0 = 0, bi1 = 0, bi2 = 0;
        const int sb = wv << 8;
        const float4* __restrict__ sp = sseed + sb;
        #pragma unroll 4
        for (int t = 0; t < 256; ++t) {
            const float4 k = sp[t];   // one broadcast read feeds both chains
            const int gi = sb + t;
            const float dA = fmaf(-uxA, k.x, fmaf(-uyA, k.y, fmaf(-uzA, k.z, k.w)));
            const float dB = fmaf(-uxB, k.x, fmaf(-uyB, k.y, fmaf(-uzB, k.z, k.w)));
            SLIM3(a0, a1, a2, ai0, ai1, ai2, dA, gi);
            SLIM3(b0, b1v, b2v, bi0, bi1, bi2, dB, gi);
        }

        smdA[wv][lane][0] = a0; smdA[wv][lane][1] = a1; smdA[wv][lane][2] = a2;
        smiA[wv][lane][0] = ai0; smiA[wv][lane][1] = ai1; smiA[wv][lane][2] = ai2;
        smdB[wv][lane][0] = b0; smdB[wv][lane][1] = b1v; smdB[wv][lane][2] = b2v;
        smiB[wv][lane][0] = bi0; smiB[wv][lane][1] = bi1; smiB[wv][lane][2] = bi2;
        __syncthreads();

        // wave 0 merges+writes point-set A; wave 1 does set B (parallel)
        if (wv < 2) {
            float (*smd)[64][3] = (wv == 0) ? smdA : smdB;
            int   (*smi)[64][3] = (wv == 0) ? smiA : smiB;
            const int p = (wv == 0) ? pA : pB;
            const float un = (wv == 0) ? unA : unB;

            float v0 = smd[0][lane][0], v1 = smd[0][lane][1], v2 = smd[0][lane][2];
            int   i0 = smi[0][lane][0], i1 = smi[0][lane][1], i2 = smi[0][lane][2];
            #pragma unroll
            for (int w = 1; w < 4; ++w) {
                #pragma unroll
                for (int kk = 0; kk < 3; ++kk) {
                    const float dd = smd[w][lane][kk];
                    const int   ss = smi[w][lane][kk];
                    INSERT3(v0, v1, v2, i0, i1, i2, dd, ss);
                }
            }
            if (p < N_) {
                const float d0 = sqrtf(fmaxf(fmaf(2.f, v0, un), 1e-12f));
                const float d1 = sqrtf(fmaxf(fmaf(2.f, v1, un), 1e-12f));
                const float d2s = sqrtf(fmaxf(fmaf(2.f, v2, un), 1e-12f));
                const float r0 = 1.f / (d0 + 1e-8f);
                const float r1 = 1.f / (d1 + 1e-8f);
                const float r2 = 1.f / (d2s + 1e-8f);
                const float rs = (r0 + r1) + r2;
                const float q0 = r0 / rs, q1 = r1 / rs, q2 = r2 / rs;
                const unsigned pk =
                    (unsigned)i0 | ((unsigned)i1 << 10) | ((unsigned)i2 << 20);
                nnres[(size_t)b * N_ + p] = make_uint4(
                    pk, __float_as_uint(q0), __float_as_uint(q1), __float_as_uint(q2));
            }
        }
    }
}

// ---------------------------------------------------------------------------
// Gather epilogue (R9 verbatim): out[b][j][p] = sum_k q_k * so5[j][idx_k]
// ---------------------------------------------------------------------------
__global__ __launch_bounds__(256) void k_gather(
    const float* __restrict__ part, const uint4* __restrict__ nnres,
    float* __restrict__ out)
{
    const int b = blockIdx.y;
    __shared__ float so5[5][M_];
    for (int v = threadIdx.x; v < 5 * M_; v += 256) {
        const int j = v >> 10, m = v & (M_ - 1);
        const float* __restrict__ pp = part + ((size_t)b * 5 + j) * M_ + m;
        so5[j][m] = (pp[0] + pp[10240]) + (pp[20480] + pp[30720]);
    }
    __syncthreads();

    const int p = (blockIdx.x << 8) + threadIdx.x;
    if (p < N_) {
        const uint4 r = nnres[(size_t)b * N_ + p];
        const int i0 = r.x & 1023, i1 = (r.x >> 10) & 1023, i2 = (r.x >> 20) & 1023;
        const float q0 = __uint_as_float(r.y);
        const float q1 = __uint_as_float(r.z);
        const float q2 = __uint_as_float(r.w);
        #pragma unroll
        for (int j = 0; j < 5; ++j) {
            out[((size_t)b * 5 + j) * N_ + p] =
                fmaf(q0, so5[j][i0], fmaf(q1, so5[j][i1], q2 * so5[j][i2]));
        }
    }
}

// ---------------------------------------------------------------------------
extern "C" void kernel_launch(void* const* d_in, const int* in_sizes, int n_in,
                              void* d_out, int out_size, void* d_ws, size_t ws_size,
                              hipStream_t stream)
{
    const float* pc    = (const float*)d_in[0];
    const float* sxyz  = (const float*)d_in[1];
    const float* feat  = (const float*)d_in[2];
    const float* w1f   = (const float*)d_in[3];
    const float* b1f   = (const float*)d_in[4];
    const float* g1f   = (const float*)d_in[5];
    const float* be1f  = (const float*)d_in[6];
    const float* mu1f  = (const float*)d_in[7];
    const float* var1f = (const float*)d_in[8];
    const float* w2f   = (const float*)d_in[9];
    const float* b2f   = (const float*)d_in[10];
    const float* w1c   = (const float*)d_in[11];
    const float* b1c   = (const float*)d_in[12];
    const float* g1c   = (const float*)d_in[13];
    const float* be1c  = (const float*)d_in[14];
    const float* mu1c  = (const float*)d_in[15];
    const float* var1c = (const float*)d_in[16];
    const float* w2c   = (const float*)d_in[17];
    const float* b2c   = (const float*)d_in[18];

    float* out  = (float*)d_out;
    float* part = (float*)d_ws;                         // 4*2*5*1024 f32 = 160 KB
    uint4* nnres = (uint4*)((char*)d_ws + 163840);      // 40000 * 16 B

    k_fused<<<dim3(GEMM_BLOCKS_ + NN_BLOCKS_), 256, 0, stream>>>(
        pc, sxyz, feat,
        w1f, b1f, g1f, be1f, mu1f, var1f, w2f, b2f,
        w1c, b1c, g1c, be1c, mu1c, var1c, w2c, b2c,
        part, nnres);

    k_gather<<<dim3((N_ + 255) / 256, B_), 256, 0, stream>>>(part, nnres, out);
}

// Round 13
// 39.879 us; speedup vs baseline: 1.0862x; 1.0862x over previous
//
#include <hip/hip_runtime.h>
#include <math.h>

#define B_ 2
#define N_ 20000
#define M_ 1024
#define C_ 256
#define BN_EPS_ 1e-5f

#define NNBLK_PER_B_ 313            // ceil(20000/64), 64 points per NN block
#define GEMM_BLOCKS_ 256            // 16 mt x 4 ot x 4 bh
#define NN_BLOCKS_   (2 * NNBLK_PER_B_)

// index-carrying sorted top-3 insert, strict < keeps earliest (lowest index).
// Cold merge path only.
#define INSERT3(vv0, vv1, vv2, ii0, ii1, ii2, dd, ss)     \
    {                                                     \
        bool c2_ = (dd) < vv2;                            \
        vv2 = c2_ ? (dd) : vv2;  ii2 = c2_ ? (ss) : ii2;  \
        bool c1_ = vv2 < vv1;                             \
        float tv_ = vv1; int ti_ = ii1;                   \
        vv1 = c1_ ? vv2 : vv1;  ii1 = c1_ ? ii2 : ii1;    \
        vv2 = c1_ ? tv_ : vv2; ii2 = c1_ ? ti_ : ii2;     \
        bool c0_ = vv1 < vv0;                             \
        tv_ = vv0; ti_ = ii0;                             \
        vv0 = c0_ ? vv1 : vv0;  ii0 = c0_ ? ii1 : ii0;    \
        vv1 = c0_ ? tv_ : vv1; ii1 = c0_ ? ti_ : ii1;     \
    }

// slim exact hot-loop insert (R9-proven state-identical to INSERT3)
#define SLIM3(vv0, vv1, vv2, ii0, ii1, ii2, dd, gg)       \
    {                                                     \
        const bool c0_ = (dd) < vv0;                      \
        const bool c1_ = (dd) < vv1;                      \
        const bool c2_ = (dd) < vv2;                      \
        ii2 = c2_ ? (c1_ ? ii1 : (gg)) : ii2;             \
        ii1 = c1_ ? (c0_ ? ii0 : (gg)) : ii1;             \
        ii0 = c0_ ? (gg) : ii0;                           \
        const float nv1_ = __builtin_amdgcn_fmed3f((dd), vv0, vv1); \
        const float nv2_ = __builtin_amdgcn_fmed3f((dd), vv1, vv2); \
        vv0 = fminf((dd), vv0);                           \
        vv1 = nv1_;                                       \
        vv2 = nv2_;                                       \
    }

// ---------------------------------------------------------------------------
// Fused kernel: blocks [0,256) run the head GEMMs -> part[],
//               blocks [256,882) run 3-NN -> nnres[].
// NN seeds are read via wave-uniform GLOBAL loads (scalar-cache path) —
// zero LDS traffic in the scan; 0.5|k|^2 computed in-loop with the exact
// staging expression tree (selection bitwise identical to R9/R11).
// ---------------------------------------------------------------------------
__global__ __launch_bounds__(256) void k_fused(
    const float* __restrict__ pc, const float* __restrict__ seed,
    const float* __restrict__ feat,
    const float* __restrict__ w1f, const float* __restrict__ b1f,
    const float* __restrict__ g1f, const float* __restrict__ be1f,
    const float* __restrict__ mu1f, const float* __restrict__ var1f,
    const float* __restrict__ w2f, const float* __restrict__ b2f,
    const float* __restrict__ w1c, const float* __restrict__ b1c,
    const float* __restrict__ g1c, const float* __restrict__ be1c,
    const float* __restrict__ mu1c, const float* __restrict__ var1c,
    const float* __restrict__ w2c, const float* __restrict__ b2c,
    float* __restrict__ part, uint4* __restrict__ nnres)
{
    __shared__ float4 smembuf[1408];          // 22528 B, union of both roles
    const int bid = blockIdx.x;
    const int tid = threadIdx.x;

    if (bid < GEMM_BLOCKS_) {
        // =================== GEMM role (R11 verbatim) ===================
        const int mt = bid & 15;
        const int ot = (bid >> 4) & 3;
        const int bh = bid >> 6;
        const int b = bh >> 1, head = bh & 1;

        const float* __restrict__ w1   = head ? w1c   : w1f;
        const float* __restrict__ b1   = head ? b1c   : b1f;
        const float* __restrict__ g1   = head ? g1c   : g1f;
        const float* __restrict__ be1  = head ? be1c  : be1f;
        const float* __restrict__ mu1  = head ? mu1c  : mu1f;
        const float* __restrict__ var1 = head ? var1c : var1f;
        const float* __restrict__ w2   = head ? w2c   : w2f;
        const float* __restrict__ b2   = head ? b2c   : b2f;
        const int nj = head ? 3 : 2;

        float* base = (float*)smembuf;
        float (*sW)[68]      = (float(*)[68])base;             // 16x68
        float (*sF)[64]      = (float(*)[64])(base + 1088);    // 16x64
        float (*sred)[3][68] = (float(*)[3][68])(base + 2112); // 16x3x68

        const int tm = tid & 15;
        const int to = tid >> 4;
        const int m0 = mt * 64, o0 = ot * 64;

        const int so  = tid >> 2;
        const int sc4 = (tid & 3) << 2;
        const float sscale = g1[o0 + so] * rsqrtf(var1[o0 + so] + BN_EPS_);
        const int fc = tid >> 4;
        const int fm = (tid & 15) << 2;

        const float* __restrict__ wrow = w1 + (size_t)(o0 + so) * C_ + sc4;
        const float* __restrict__ frow = feat + ((size_t)b * C_ + fc) * M_ + m0 + fm;

        float4 wv = *(const float4*)(wrow);
        float4 fv = *(const float4*)(frow);

        float2 acc2[4][2] = {};

        for (int c0 = 0; c0 < C_; c0 += 16) {
            __syncthreads();
            sW[sc4 + 0][so] = wv.x * sscale;
            sW[sc4 + 1][so] = wv.y * sscale;
            sW[sc4 + 2][so] = wv.z * sscale;
            sW[sc4 + 3][so] = wv.w * sscale;
            *(float4*)&sF[fc][fm] = fv;
            __syncthreads();
            const int cn = (c0 + 16 < C_) ? c0 + 16 : c0;
            wv = *(const float4*)(wrow + cn);
            fv = *(const float4*)(frow + (size_t)cn * M_);
            #pragma unroll
            for (int cc = 0; cc < 16; ++cc) {
                float4 w4 = *(const float4*)&sW[cc][to << 2];
                float4 f4 = *(const float4*)&sF[cc][tm << 2];
                const float2 f01 = make_float2(f4.x, f4.y);
                const float2 f23 = make_float2(f4.z, f4.w);
                float wr[4] = {w4.x, w4.y, w4.z, w4.w};
                #pragma unroll
                for (int i = 0; i < 4; ++i) {
                    const float2 wb = make_float2(wr[i], wr[i]);
                    acc2[i][0] = acc2[i][0] + wb * f01;
                    acc2[i][1] = acc2[i][1] + wb * f23;
                }
            }
        }

        float r[4][4];
        #pragma unroll
        for (int i = 0; i < 4; ++i) {
            const int o = o0 + (to << 2) + i;
            const float sc = g1[o] * rsqrtf(var1[o] + BN_EPS_);
            const float bb = (b1[o] - mu1[o]) * sc + be1[o];
            r[i][0] = fmaxf(acc2[i][0].x + bb, 0.f);
            r[i][1] = fmaxf(acc2[i][0].y + bb, 0.f);
            r[i][2] = fmaxf(acc2[i][1].x + bb, 0.f);
            r[i][3] = fmaxf(acc2[i][1].y + bb, 0.f);
        }

        __syncthreads();
        for (int j = 0; j < nj; ++j) {
            float s[4] = {0.f, 0.f, 0.f, 0.f};
            #pragma unroll
            for (int i = 0; i < 4; ++i) {
                const float w = w2[(size_t)j * C_ + o0 + (to << 2) + i];
                #pragma unroll
                for (int jj = 0; jj < 4; ++jj)
                    s[jj] = fmaf(w, r[i][jj], s[jj]);
            }
            *(float4*)&sred[to][j][tm << 2] = *(float4*)s;
        }
        __syncthreads();

        if (tid < nj * 64) {
            const int j = tid >> 6, m = tid & 63;
            float a = 0.f;
            #pragma unroll
            for (int t = 0; t < 16; ++t) a += sred[t][j][m];
            if (ot == 0) a += b2[j];
            const int jg = head ? (2 + j) : j;
            part[(((size_t)ot * B_ + b) * 5 + jg) * M_ + m0 + m] = a;
        }
    } else {
        // =================== NN role: scalar-path seeds, no LDS scan ==========
        const int nb = bid - GEMM_BLOCKS_;
        const int b = (nb >= NNBLK_PER_B_) ? 1 : 0;
        const int p0 = (nb - b * NNBLK_PER_B_) << 6;
        const int wv = tid >> 6, lane = tid & 63;

        float* fb = (float*)smembuf;
        float (*smd)[64][3] = (float(*)[64][3])fb;          // 4x64x3 floats
        int   (*smi)[64][3] = (int(*)[64][3])(fb + 768);    // 4x64x3 ints

        const int p = p0 + lane;
        const int pcl = (p < N_) ? p : (N_ - 1);
        const float ux = pc[((size_t)b * N_ + pcl) * 3 + 0];
        const float uy = pc[((size_t)b * N_ + pcl) * 3 + 1];
        const float uz = pc[((size_t)b * N_ + pcl) * 3 + 2];
        const float un = (ux * ux + uy * uy) + uz * uz;

        float v0 = 3.4e38f, v1 = 3.4e38f, v2 = 3.4e38f;
        int i0 = 0, i1 = 0, i2 = 0;
        const int sb = wv << 8;
        // wave-uniform seed base -> scalar-cache loads, zero LDS traffic
        const int sbu = __builtin_amdgcn_readfirstlane(sb);
        const float* __restrict__ sp = seed + ((size_t)b * M_ + (size_t)sbu) * 3;

        #pragma unroll 8
        for (int t = 0; t < 256; ++t) {
            const float kx = sp[3 * t + 0];
            const float ky = sp[3 * t + 1];
            const float kz = sp[3 * t + 2];
            // exact staging expression tree -> metric bitwise identical to R9/R11
            const float kw = 0.5f * ((kx * kx + ky * ky) + kz * kz);
            const float d = fmaf(-ux, kx, fmaf(-uy, ky, fmaf(-uz, kz, kw)));
            SLIM3(v0, v1, v2, i0, i1, i2, d, sb + t);
        }

        smd[wv][lane][0] = v0; smd[wv][lane][1] = v1; smd[wv][lane][2] = v2;
        smi[wv][lane][0] = i0; smi[wv][lane][1] = i1; smi[wv][lane][2] = i2;
        __syncthreads();

        if (wv == 0 && p < N_) {
            #pragma unroll
            for (int w = 1; w < 4; ++w) {
                #pragma unroll
                for (int kk = 0; kk < 3; ++kk) {
                    const float dd = smd[w][lane][kk];
                    const int   ss = smi[w][lane][kk];
                    INSERT3(v0, v1, v2, i0, i1, i2, dd, ss);
                }
            }
            const float d0 = sqrtf(fmaxf(fmaf(2.f, v0, un), 1e-12f));
            const float d1 = sqrtf(fmaxf(fmaf(2.f, v1, un), 1e-12f));
            const float d2s = sqrtf(fmaxf(fmaf(2.f, v2, un), 1e-12f));
            const float r0 = 1.f / (d0 + 1e-8f);
            const float r1 = 1.f / (d1 + 1e-8f);
            const float r2 = 1.f / (d2s + 1e-8f);
            const float rs = (r0 + r1) + r2;
            const float q0 = r0 / rs, q1 = r1 / rs, q2 = r2 / rs;
            const unsigned pk =
                (unsigned)i0 | ((unsigned)i1 << 10) | ((unsigned)i2 << 20);
            nnres[(size_t)b * N_ + p] = make_uint4(
                pk, __float_as_uint(q0), __float_as_uint(q1), __float_as_uint(q2));
        }
    }
}

// ---------------------------------------------------------------------------
// Gather epilogue (R9 verbatim): out[b][j][p] = sum_k q_k * so5[j][idx_k]
// ---------------------------------------------------------------------------
__global__ __launch_bounds__(256) void k_gather(
    const float* __restrict__ part, const uint4* __restrict__ nnres,
    float* __restrict__ out)
{
    const int b = blockIdx.y;
    __shared__ float so5[5][M_];
    for (int v = threadIdx.x; v < 5 * M_; v += 256) {
        const int j = v >> 10, m = v & (M_ - 1);
        const float* __restrict__ pp = part + ((size_t)b * 5 + j) * M_ + m;
        so5[j][m] = (pp[0] + pp[10240]) + (pp[20480] + pp[30720]);
    }
    __syncthreads();

    const int p = (blockIdx.x << 8) + threadIdx.x;
    if (p < N_) {
        const uint4 r = nnres[(size_t)b * N_ + p];
        const int i0 = r.x & 1023, i1 = (r.x >> 10) & 1023, i2 = (r.x >> 20) & 1023;
        const float q0 = __uint_as_float(r.y);
        const float q1 = __uint_as_float(r.z);
        const float q2 = __uint_as_float(r.w);
        #pragma unroll
        for (int j = 0; j < 5; ++j) {
            out[((size_t)b * 5 + j) * N_ + p] =
                fmaf(q0, so5[j][i0], fmaf(q1, so5[j][i1], q2 * so5[j][i2]));
        }
    }
}

// ---------------------------------------------------------------------------
extern "C" void kernel_launch(void* const* d_in, const int* in_sizes, int n_in,
                              void* d_out, int out_size, void* d_ws, size_t ws_size,
                              hipStream_t stream)
{
    const float* pc    = (const float*)d_in[0];
    const float* sxyz  = (const float*)d_in[1];
    const float* feat  = (const float*)d_in[2];
    const float* w1f   = (const float*)d_in[3];
    const float* b1f   = (const float*)d_in[4];
    const float* g1f   = (const float*)d_in[5];
    const float* be1f  = (const float*)d_in[6];
    const float* mu1f  = (const float*)d_in[7];
    const float* var1f = (const float*)d_in[8];
    const float* w2f   = (const float*)d_in[9];
    const float* b2f   = (const float*)d_in[10];
    const float* w1c   = (const float*)d_in[11];
    const float* b1c   = (const float*)d_in[12];
    const float* g1c   = (const float*)d_in[13];
    const float* be1c  = (const float*)d_in[14];
    const float* mu1c  = (const float*)d_in[15];
    const float* var1c = (const float*)d_in[16];
    const float* w2c   = (const float*)d_in[17];
    const float* b2c   = (const float*)d_in[18];

    float* out  = (float*)d_out;
    float* part = (float*)d_ws;                         // 4*2*5*1024 f32 = 160 KB
    uint4* nnres = (uint4*)((char*)d_ws + 163840);      // 40000 * 16 B

    k_fused<<<dim3(GEMM_BLOCKS_ + NN_BLOCKS_), 256, 0, stream>>>(
        pc, sxyz, feat,
        w1f, b1f, g1f, be1f, mu1f, var1f, w2f, b2f,
        w1c, b1c, g1c, be1c, mu1c, var1c, w2c, b2c,
        part, nnres);

    k_gather<<<dim3((N_ + 255) / 256, B_), 256, 0, stream>>>(part, nnres, out);
}